// Round 1
// baseline (236.128 us; speedup 1.0000x reference)
//
#include <hip/hip_runtime.h>
#include <hip/hip_bf16.h>

#define NN 6144
#define DLAT 512

typedef __attribute__((ext_vector_type(8))) short bf16x8;
typedef __attribute__((ext_vector_type(4))) float f32x4;

// ---------------- prep: pack coords+alpha into float4 ----------------
__global__ __launch_bounds__(256) void prep_kernel(const float* __restrict__ coords,
                                                   const float* __restrict__ alpha,
                                                   float4* __restrict__ pre) {
  int j = blockIdx.x * 256 + threadIdx.x;
  if (j < NN) {
    pre[j] = make_float4(coords[3*j], coords[3*j+1], coords[3*j+2], alpha[j]);
  }
}

// ---------------- build normalized K (fp32 to d_out, bf16 to ws) ----------------
template<int USE_WS>
__global__ __launch_bounds__(256) void buildk_kernel(const float* __restrict__ coords,
                                                     const float* __restrict__ alpha,
                                                     const float4* __restrict__ pre,
                                                     float* __restrict__ Kout,
                                                     __hip_bfloat16* __restrict__ Kbf) {
  const int i = blockIdx.x;
  const int t = threadIdx.x;
  float ci0, ci1, ci2, ai;
  if constexpr (USE_WS) {
    float4 p = pre[i]; ci0 = p.x; ci1 = p.y; ci2 = p.z; ai = p.w;
  } else {
    ci0 = coords[3*i]; ci1 = coords[3*i+1]; ci2 = coords[3*i+2]; ai = alpha[i];
  }
  const float sqi = ci0*ci0 + ci1*ci1 + ci2*ci2;
  float vals[24];
  float lsum = 0.f;
#pragma unroll
  for (int it = 0; it < 24; ++it) {
    const int j = t + it*256;
    float c0, c1, c2, aj;
    if constexpr (USE_WS) {
      float4 p = pre[j]; c0 = p.x; c1 = p.y; c2 = p.z; aj = p.w;
    } else {
      c0 = coords[3*j]; c1 = coords[3*j+1]; c2 = coords[3*j+2]; aj = alpha[j];
    }
    float sqj = c0*c0 + c1*c1 + c2*c2;
    float dot = ci0*c0 + ci1*c1 + ci2*c2;
    float d2 = sqi + sqj - 2.f*dot;                 // same Gram trick as reference
    float D = sqrtf(fmaxf(d2, 1e-12f)) + 1e-6f;
    float a = 0.5f*(ai + aj);
    float p = __expf(-a * __logf(D));               // D^-a
    p = fminf(fmaxf(p, 1e-8f), 1000.f);
    float kv = p * __expf(D * (-1.f/12.f));
    if (j == i) kv = 0.f;                           // zero diagonal
    vals[it] = kv;
    lsum += kv;
  }
  // block-wide row-sum reduction
#pragma unroll
  for (int off = 32; off > 0; off >>= 1) lsum += __shfl_down(lsum, off);
  __shared__ float red[4];
  if ((t & 63) == 0) red[t >> 6] = lsum;
  __syncthreads();
  const float inv = 1.f / (red[0] + red[1] + red[2] + red[3] + 1e-8f);
  const size_t rowoff = (size_t)i * NN;
#pragma unroll
  for (int it = 0; it < 24; ++it) {
    const int j = t + it*256;
    float v = vals[it] * inv;
    Kout[rowoff + j] = v;
    if constexpr (USE_WS) Kbf[rowoff + j] = __float2bfloat16(v);
  }
}

// ---------------- transpose latent -> bf16 latentT [512][6144] ----------------
__global__ __launch_bounds__(256) void tlat_kernel(const float* __restrict__ latent,
                                                   __hip_bfloat16* __restrict__ lt) {
  __shared__ __hip_bfloat16 tile[64][65];
  const int t = threadIdx.x;
  const int kb = blockIdx.x * 64;   // k tile
  const int nb = blockIdx.y * 64;   // latent-col tile
#pragma unroll
  for (int s = 0; s < 4; ++s) {
    int idx = t + s*256;
    int r = idx >> 4;               // k-row 0..63
    int c4 = idx & 15;
    float4 v = *(const float4*)&latent[(size_t)(kb + r)*DLAT + nb + c4*4];
    tile[c4*4+0][r] = __float2bfloat16(v.x);
    tile[c4*4+1][r] = __float2bfloat16(v.y);
    tile[c4*4+2][r] = __float2bfloat16(v.z);
    tile[c4*4+3][r] = __float2bfloat16(v.w);
  }
  __syncthreads();
#pragma unroll
  for (int s = 0; s < 4; ++s) {
    int idx = t + s*256;
    int rr = idx >> 4;              // n-row
    int cb = (idx & 15)*4;          // k-col
#pragma unroll
    for (int q = 0; q < 4; ++q)
      lt[(size_t)(nb + rr)*NN + kb + cb + q] = tile[rr][cb + q];
  }
}

// ---------------- GEMM out[6144,512] = K @ latent via bf16 MFMA ----------------
#define BM 128
#define BN 64
#define BK 64
#define NKT (NN / BK)

template<int WS>
__global__ __launch_bounds__(256) void gemm_kernel(const __hip_bfloat16* __restrict__ Abf,
                                                   const __hip_bfloat16* __restrict__ Btbf,
                                                   const float* __restrict__ Afp,
                                                   const float* __restrict__ Bfp,
                                                   float* __restrict__ out) {
  __shared__ __align__(16) short As[2][BM][BK + 8];
  __shared__ __align__(16) short Bs[2][BN][BK + 8];
  const int t = threadIdx.x;
  const int rowBase = blockIdx.x * BM;
  const int colBase = blockIdx.y * BN;
  const int lane = t & 63;
  const int w  = t >> 6;
  const int wr = w >> 1;            // 0..1 (64-row half)
  const int wc = w & 1;             // 0..1 (32-col half)
  const int fr = lane & 15;
  const int fk = lane >> 4;

  int4 ra[4], rb[2];

  auto load_regs = [&](int kt) {
    if constexpr (WS) {
#pragma unroll
      for (int s = 0; s < 4; ++s) {
        int c = t + s*256; int r = c >> 3, q = c & 7;
        ra[s] = *(const int4*)((const char*)Abf + ((size_t)(rowBase + r)*NN + kt*BK + q*8)*2);
      }
#pragma unroll
      for (int s = 0; s < 2; ++s) {
        int c = t + s*256; int r = c >> 3, q = c & 7;
        rb[s] = *(const int4*)((const char*)Btbf + ((size_t)(colBase + r)*NN + kt*BK + q*8)*2);
      }
    } else {
#pragma unroll
      for (int s = 0; s < 4; ++s) {
        int c = t + s*256; int r = c >> 3, q = c & 7;
        const float* src = Afp + (size_t)(rowBase + r)*NN + kt*BK + q*8;
        float4 f0 = *(const float4*)src;
        float4 f1 = *(const float4*)(src + 4);
        __hip_bfloat16 h[8];
        h[0]=__float2bfloat16(f0.x); h[1]=__float2bfloat16(f0.y);
        h[2]=__float2bfloat16(f0.z); h[3]=__float2bfloat16(f0.w);
        h[4]=__float2bfloat16(f1.x); h[5]=__float2bfloat16(f1.y);
        h[6]=__float2bfloat16(f1.z); h[7]=__float2bfloat16(f1.w);
        ra[s] = *(const int4*)h;
      }
#pragma unroll
      for (int s = 0; s < 2; ++s) {
        int c = t + s*256; int r = c >> 3, q = c & 7;
        const float* src = Bfp + (size_t)(kt*BK + q*8)*DLAT + colBase + r;
        __hip_bfloat16 h[8];
#pragma unroll
        for (int i2 = 0; i2 < 8; ++i2) h[i2] = __float2bfloat16(src[(size_t)i2*DLAT]);
        rb[s] = *(const int4*)h;
      }
    }
  };

  auto write_tiles = [&](int buf) {
#pragma unroll
    for (int s = 0; s < 4; ++s) {
      int c = t + s*256; int r = c >> 3, q = c & 7;
      *(int4*)&As[buf][r][q*8] = ra[s];
    }
#pragma unroll
    for (int s = 0; s < 2; ++s) {
      int c = t + s*256; int r = c >> 3, q = c & 7;
      *(int4*)&Bs[buf][r][q*8] = rb[s];
    }
  };

  f32x4 acc[4][2];
#pragma unroll
  for (int m = 0; m < 4; ++m)
#pragma unroll
    for (int n = 0; n < 2; ++n) acc[m][n] = (f32x4){0.f, 0.f, 0.f, 0.f};

  auto compute = [&](int buf) {
#pragma unroll
    for (int ks = 0; ks < 2; ++ks) {
      bf16x8 av[4], bv[2];
#pragma unroll
      for (int m = 0; m < 4; ++m)
        av[m] = *(const bf16x8*)&As[buf][wr*64 + m*16 + fr][ks*32 + fk*8];
#pragma unroll
      for (int n = 0; n < 2; ++n)
        bv[n] = *(const bf16x8*)&Bs[buf][wc*32 + n*16 + fr][ks*32 + fk*8];
#pragma unroll
      for (int m = 0; m < 4; ++m)
#pragma unroll
        for (int n = 0; n < 2; ++n)
          acc[m][n] = __builtin_amdgcn_mfma_f32_16x16x32_bf16(av[m], bv[n], acc[m][n], 0, 0, 0);
    }
  };

  load_regs(0);
  write_tiles(0);
  __syncthreads();
  int buf = 0;
  for (int kt = 0; kt < NKT; ++kt) {
    if (kt + 1 < NKT) load_regs(kt + 1);   // issue global loads early (hide under MFMA)
    compute(buf);
    if (kt + 1 < NKT) write_tiles(buf ^ 1);
    __syncthreads();
    buf ^= 1;
  }

#pragma unroll
  for (int m = 0; m < 4; ++m)
#pragma unroll
    for (int n = 0; n < 2; ++n) {
      const int row0 = rowBase + wr*64 + m*16 + fk*4;
      const int col  = colBase + wc*32 + n*16 + fr;
#pragma unroll
      for (int i2 = 0; i2 < 4; ++i2)
        out[(size_t)(row0 + i2)*DLAT + col] = acc[m][n][i2];
    }
}

extern "C" void kernel_launch(void* const* d_in, const int* in_sizes, int n_in,
                              void* d_out, int out_size, void* d_ws, size_t ws_size,
                              hipStream_t stream) {
  const float* latent = (const float*)d_in[0];
  const float* coords = (const float*)d_in[1];
  const float* alpha  = (const float*)d_in[2];
  float* out  = (float*)d_out;                       // [6144,512]
  float* Kout = out + (size_t)NN * DLAT;             // [6144,6144]

  const size_t needK = (size_t)NN * NN * 2;          // bf16 K
  const size_t needL = (size_t)DLAT * NN * 2;        // bf16 latentT
  const size_t needP = (size_t)NN * 16;              // packed coords+alpha
  const bool ws_ok = ws_size >= needK + needL + needP;

  if (ws_ok) {
    __hip_bfloat16* Kbf = (__hip_bfloat16*)d_ws;
    __hip_bfloat16* LT  = (__hip_bfloat16*)((char*)d_ws + needK);
    float4* pre = (float4*)((char*)d_ws + needK + needL);
    prep_kernel<<<NN/256, 256, 0, stream>>>(coords, alpha, pre);
    buildk_kernel<1><<<NN, 256, 0, stream>>>(coords, alpha, pre, Kout, Kbf);
    tlat_kernel<<<dim3(NN/64, DLAT/64), 256, 0, stream>>>(latent, LT);
    gemm_kernel<1><<<dim3(NN/BM, DLAT/BN), 256, 0, stream>>>(Kbf, LT, nullptr, nullptr, out);
  } else {
    buildk_kernel<0><<<NN, 256, 0, stream>>>(coords, alpha, nullptr, Kout, nullptr);
    gemm_kernel<0><<<dim3(NN/BM, DLAT/BN), 256, 0, stream>>>(nullptr, nullptr, Kout, latent, out);
  }
}

// Round 2
// 147.464 us; speedup vs baseline: 1.6013x; 1.6013x over previous
//
#include <hip/hip_runtime.h>
#include <hip/hip_bf16.h>

#define NN 6144
#define DLAT 512

typedef __attribute__((ext_vector_type(8))) short bf16x8;
typedef __attribute__((ext_vector_type(4))) float f32x4;

#define GLOAD_LDS16(g, l) \
  __builtin_amdgcn_global_load_lds((const __attribute__((address_space(1))) unsigned int*)(g), \
                                   (__attribute__((address_space(3))) unsigned int*)(l), 16, 0, 0)

// ---------------- prep: pack coords+alpha into float4 ----------------
__global__ __launch_bounds__(256) void prep_kernel(const float* __restrict__ coords,
                                                   const float* __restrict__ alpha,
                                                   float4* __restrict__ pre) {
  int j = blockIdx.x * 256 + threadIdx.x;
  if (j < NN) {
    pre[j] = make_float4(coords[3*j], coords[3*j+1], coords[3*j+2], alpha[j]);
  }
}

// ---------------- build normalized K (fp32 to d_out, bf16 to ws) ----------------
template<int USE_WS>
__global__ __launch_bounds__(256) void buildk_kernel(const float* __restrict__ coords,
                                                     const float* __restrict__ alpha,
                                                     const float4* __restrict__ pre,
                                                     float* __restrict__ Kout,
                                                     __hip_bfloat16* __restrict__ Kbf) {
  const int i = blockIdx.x;
  const int t = threadIdx.x;
  float ci0, ci1, ci2, ai;
  if constexpr (USE_WS) {
    float4 p = pre[i]; ci0 = p.x; ci1 = p.y; ci2 = p.z; ai = p.w;
  } else {
    ci0 = coords[3*i]; ci1 = coords[3*i+1]; ci2 = coords[3*i+2]; ai = alpha[i];
  }
  const float sqi = ci0*ci0 + ci1*ci1 + ci2*ci2;
  float vals[24];
  float lsum = 0.f;
#pragma unroll
  for (int it = 0; it < 24; ++it) {
    const int j = t + it*256;
    float c0, c1, c2, aj;
    if constexpr (USE_WS) {
      float4 p = pre[j]; c0 = p.x; c1 = p.y; c2 = p.z; aj = p.w;
    } else {
      c0 = coords[3*j]; c1 = coords[3*j+1]; c2 = coords[3*j+2]; aj = alpha[j];
    }
    float sqj = c0*c0 + c1*c1 + c2*c2;
    float dot = ci0*c0 + ci1*c1 + ci2*c2;
    float d2 = sqi + sqj - 2.f*dot;                 // same Gram trick as reference
    float D = sqrtf(fmaxf(d2, 1e-12f)) + 1e-6f;
    float a = 0.5f*(ai + aj);
    float p = __expf(-a * __logf(D));               // D^-a
    p = fminf(fmaxf(p, 1e-8f), 1000.f);
    float kv = p * __expf(D * (-1.f/12.f));
    if (j == i) kv = 0.f;                           // zero diagonal
    vals[it] = kv;
    lsum += kv;
  }
#pragma unroll
  for (int off = 32; off > 0; off >>= 1) lsum += __shfl_down(lsum, off);
  __shared__ float red[4];
  if ((t & 63) == 0) red[t >> 6] = lsum;
  __syncthreads();
  const float inv = 1.f / (red[0] + red[1] + red[2] + red[3] + 1e-8f);
  const size_t rowoff = (size_t)i * NN;
#pragma unroll
  for (int it = 0; it < 24; ++it) {
    const int j = t + it*256;
    float v = vals[it] * inv;
    Kout[rowoff + j] = v;
    if constexpr (USE_WS) Kbf[rowoff + j] = __float2bfloat16(v);
  }
}

// ---------------- transpose latent -> bf16 latentT [512][6144] ----------------
__global__ __launch_bounds__(256) void tlat_kernel(const float* __restrict__ latent,
                                                   __hip_bfloat16* __restrict__ lt) {
  __shared__ __hip_bfloat16 tile[64][65];
  const int t = threadIdx.x;
  const int kb = blockIdx.x * 64;
  const int nb = blockIdx.y * 64;
#pragma unroll
  for (int s = 0; s < 4; ++s) {
    int idx = t + s*256;
    int r = idx >> 4;
    int c4 = idx & 15;
    float4 v = *(const float4*)&latent[(size_t)(kb + r)*DLAT + nb + c4*4];
    tile[c4*4+0][r] = __float2bfloat16(v.x);
    tile[c4*4+1][r] = __float2bfloat16(v.y);
    tile[c4*4+2][r] = __float2bfloat16(v.z);
    tile[c4*4+3][r] = __float2bfloat16(v.w);
  }
  __syncthreads();
#pragma unroll
  for (int s = 0; s < 4; ++s) {
    int idx = t + s*256;
    int rr = idx >> 4;
    int cb = (idx & 15)*4;
#pragma unroll
    for (int q = 0; q < 4; ++q)
      lt[(size_t)(nb + rr)*NN + kb + cb + q] = tile[rr][cb + q];
  }
}

// ---------------- GEMM: m97 structure, 128x128 tile, BK=64, split-K ----------------
// A = Kbf [NN][NN] bf16 row-major, B = LT [DLAT][NN] bf16 (latent^T, K-major)
// out = partials[z][NN][DLAT] fp32 (SPLIT>1) or out[NN][DLAT] (SPLIT==1)
template<int SPLIT>
__global__ __launch_bounds__(256) void gemm_split_kernel(const __hip_bfloat16* __restrict__ A,
                                                         const __hip_bfloat16* __restrict__ B,
                                                         float* __restrict__ outp) {
  // 16B-granule XOR swizzle: LDS[row][slot] holds global granule (slot ^ (row&7)).
  __shared__ __align__(16) short As[128*64];
  __shared__ __align__(16) short Bs[128*64];

  const int nwg = 48 * 4 * SPLIT;
  const int bx = blockIdx.x;
  const int wg = (bx % 8) * (nwg / 8) + bx / 8;   // XCD-chunked (nwg%8==0 for all SPLIT)
  const int row = wg / (4 * SPLIT);
  const int rem = wg % (4 * SPLIT);
  const int z   = rem / 4;                         // K-split index
  const int col = rem % 4;                         // consecutive wg share the A panel
  const int rowBase = row * 128;
  const int colBase = col * 128;
  const int k0 = z * (NN / SPLIT);
  const int KSTEPS = (NN / SPLIT) / 64;

  const int t = threadIdx.x;
  const int lane = t & 63;
  const int w = t >> 6;
  const int wr = w >> 1;          // wave row 0..1 (64 rows each)
  const int wc = w & 1;           // wave col 0..1 (64 cols each)
  const int fr = lane & 15;
  const int fk = lane >> 4;

  // per-lane source granule with inverse swizzle: slot l&7 at row-chunk l>>3
  const int srcg = (((lane & 7) ^ (lane >> 3)) << 4);   // byte offset within row's 128B
  const int lrow = lane >> 3;                            // row within 8-row chunk

  const char* Ab = (const char*)A;
  const char* Bb = (const char*)B;

  auto stage = [&](const char* src, short* dst, int rb, int kbyte) {
#pragma unroll
    for (int s = 0; s < 4; ++s) {
      const int c = w * 4 + s;                           // chunk 0..15 (8 rows each)
      const size_t goff = (size_t)(rb + c * 8 + lrow) * (NN * 2) + kbyte + srcg;
      GLOAD_LDS16(src + goff, dst + c * 512);
    }
  };

  // swizzled read address: byte = row*128 + ((gran ^ (row&7))<<4)
  auto rd = [&](const short* base, int r, int g) -> bf16x8 {
    return *(const bf16x8*)((const char*)base + r * 128 + (((g ^ (r & 7))) << 4));
  };

  f32x4 acc[4][4];
#pragma unroll
  for (int m = 0; m < 4; ++m)
#pragma unroll
    for (int n = 0; n < 4; ++n) acc[m][n] = (f32x4){0.f, 0.f, 0.f, 0.f};

  for (int kt = 0; kt < KSTEPS; ++kt) {
    const int kbyte = (k0 + kt * 64) * 2;
    stage(Ab, As, rowBase, kbyte);
    stage(Bb, Bs, colBase, kbyte);
    __syncthreads();               // drains vmcnt -> LDS tiles valid
#pragma unroll
    for (int ks = 0; ks < 2; ++ks) {
      bf16x8 av[4], bv[4];
#pragma unroll
      for (int m = 0; m < 4; ++m) av[m] = rd(As, wr*64 + m*16 + fr, ks*4 + fk);
#pragma unroll
      for (int n = 0; n < 4; ++n) bv[n] = rd(Bs, wc*64 + n*16 + fr, ks*4 + fk);
#pragma unroll
      for (int m = 0; m < 4; ++m)
#pragma unroll
        for (int n = 0; n < 4; ++n)
          acc[m][n] = __builtin_amdgcn_mfma_f32_16x16x32_bf16(av[m], bv[n], acc[m][n], 0, 0, 0);
    }
    __syncthreads();               // all waves done reading before next overwrite
  }

  float* dst = outp + (SPLIT > 1 ? (size_t)z * NN * DLAT : 0);
#pragma unroll
  for (int m = 0; m < 4; ++m)
#pragma unroll
    for (int n = 0; n < 4; ++n) {
      const int row0 = rowBase + wr*64 + m*16 + fk*4;
      const int c0   = colBase + wc*64 + n*16 + fr;
#pragma unroll
      for (int i2 = 0; i2 < 4; ++i2)
        dst[(size_t)(row0 + i2) * DLAT + c0] = acc[m][n][i2];
    }
}

// ---------------- reduce split-K partials ----------------
__global__ __launch_bounds__(256) void reduce_kernel(const float4* __restrict__ parts,
                                                     float4* __restrict__ out, int S) {
  const size_t stride = (size_t)NN * DLAT / 4;
  for (size_t idx = (size_t)blockIdx.x * 256 + threadIdx.x; idx < stride;
       idx += (size_t)gridDim.x * 256) {
    float4 a = parts[idx];
    for (int zz = 1; zz < S; ++zz) {
      float4 b = parts[idx + (size_t)zz * stride];
      a.x += b.x; a.y += b.y; a.z += b.z; a.w += b.w;
    }
    out[idx] = a;
  }
}

// ---------------- fallback fp32 GEMM (tiny-ws safety net) ----------------
__global__ __launch_bounds__(256) void gemm_fallback(const float* __restrict__ Afp,
                                                     const float* __restrict__ Bfp,
                                                     float* __restrict__ out) {
  __shared__ __align__(16) short As[2][128][72];
  __shared__ __align__(16) short Bs[2][64][72];
  const int t = threadIdx.x;
  const int rowBase = blockIdx.x * 128;
  const int colBase = blockIdx.y * 64;
  const int lane = t & 63;
  const int w  = t >> 6;
  const int wr = w >> 1;
  const int wc = w & 1;
  const int fr = lane & 15;
  const int fk = lane >> 4;
  int4 ra[4], rb[2];

  auto load_regs = [&](int kt) {
#pragma unroll
    for (int s = 0; s < 4; ++s) {
      int c = t + s*256; int r = c >> 3, q = c & 7;
      const float* src = Afp + (size_t)(rowBase + r)*NN + kt*64 + q*8;
      float4 f0 = *(const float4*)src;
      float4 f1 = *(const float4*)(src + 4);
      __hip_bfloat16 h[8];
      h[0]=__float2bfloat16(f0.x); h[1]=__float2bfloat16(f0.y);
      h[2]=__float2bfloat16(f0.z); h[3]=__float2bfloat16(f0.w);
      h[4]=__float2bfloat16(f1.x); h[5]=__float2bfloat16(f1.y);
      h[6]=__float2bfloat16(f1.z); h[7]=__float2bfloat16(f1.w);
      ra[s] = *(const int4*)h;
    }
#pragma unroll
    for (int s = 0; s < 2; ++s) {
      int c = t + s*256; int r = c >> 3, q = c & 7;
      const float* src = Bfp + (size_t)(kt*64 + q*8)*DLAT + colBase + r;
      __hip_bfloat16 h[8];
#pragma unroll
      for (int i2 = 0; i2 < 8; ++i2) h[i2] = __float2bfloat16(src[(size_t)i2*DLAT]);
      rb[s] = *(const int4*)h;
    }
  };
  auto write_tiles = [&](int buf) {
#pragma unroll
    for (int s = 0; s < 4; ++s) {
      int c = t + s*256; int r = c >> 3, q = c & 7;
      *(int4*)&As[buf][r][q*8] = ra[s];
    }
#pragma unroll
    for (int s = 0; s < 2; ++s) {
      int c = t + s*256; int r = c >> 3, q = c & 7;
      *(int4*)&Bs[buf][r][q*8] = rb[s];
    }
  };
  f32x4 acc[4][2];
#pragma unroll
  for (int m = 0; m < 4; ++m)
#pragma unroll
    for (int n = 0; n < 2; ++n) acc[m][n] = (f32x4){0.f,0.f,0.f,0.f};
  auto compute = [&](int buf) {
#pragma unroll
    for (int ks = 0; ks < 2; ++ks) {
      bf16x8 av[4], bv[2];
#pragma unroll
      for (int m = 0; m < 4; ++m) av[m] = *(const bf16x8*)&As[buf][wr*64 + m*16 + fr][ks*32 + fk*8];
#pragma unroll
      for (int n = 0; n < 2; ++n) bv[n] = *(const bf16x8*)&Bs[buf][wc*32 + n*16 + fr][ks*32 + fk*8];
#pragma unroll
      for (int m = 0; m < 4; ++m)
#pragma unroll
        for (int n = 0; n < 2; ++n)
          acc[m][n] = __builtin_amdgcn_mfma_f32_16x16x32_bf16(av[m], bv[n], acc[m][n], 0, 0, 0);
    }
  };
  load_regs(0); write_tiles(0); __syncthreads();
  int buf = 0;
  for (int kt = 0; kt < 96; ++kt) {
    if (kt + 1 < 96) load_regs(kt + 1);
    compute(buf);
    if (kt + 1 < 96) write_tiles(buf ^ 1);
    __syncthreads();
    buf ^= 1;
  }
#pragma unroll
  for (int m = 0; m < 4; ++m)
#pragma unroll
    for (int n = 0; n < 2; ++n) {
      const int row0 = rowBase + wr*64 + m*16 + fk*4;
      const int c0   = colBase + wc*32 + n*16 + fr;
#pragma unroll
      for (int i2 = 0; i2 < 4; ++i2)
        out[(size_t)(row0 + i2)*DLAT + c0] = acc[m][n][i2];
    }
}

extern "C" void kernel_launch(void* const* d_in, const int* in_sizes, int n_in,
                              void* d_out, int out_size, void* d_ws, size_t ws_size,
                              hipStream_t stream) {
  const float* latent = (const float*)d_in[0];
  const float* coords = (const float*)d_in[1];
  const float* alpha  = (const float*)d_in[2];
  float* out  = (float*)d_out;                       // [6144,512]
  float* Kout = out + (size_t)NN * DLAT;             // [6144,6144]

  const size_t needK = (size_t)NN * NN * 2;          // bf16 K
  const size_t needL = (size_t)DLAT * NN * 2;        // bf16 latentT
  const size_t needP = (size_t)NN * 16;              // packed coords+alpha
  const size_t base  = needK + needL + needP;
  const size_t partB = (size_t)NN * DLAT * 4;        // one fp32 partial

  if (ws_size >= base) {
    __hip_bfloat16* Kbf = (__hip_bfloat16*)d_ws;
    __hip_bfloat16* LT  = (__hip_bfloat16*)((char*)d_ws + needK);
    float4* pre = (float4*)((char*)d_ws + needK + needL);
    float* parts = (float*)((char*)d_ws + base);

    prep_kernel<<<NN/256, 256, 0, stream>>>(coords, alpha, pre);
    buildk_kernel<1><<<NN, 256, 0, stream>>>(coords, alpha, pre, Kout, Kbf);
    tlat_kernel<<<dim3(NN/64, DLAT/64), 256, 0, stream>>>(latent, LT);

    if (ws_size >= base + 4 * partB) {
      gemm_split_kernel<4><<<48*4*4, 256, 0, stream>>>(Kbf, LT, parts);
      reduce_kernel<<<768, 256, 0, stream>>>((const float4*)parts, (float4*)out, 4);
    } else if (ws_size >= base + 2 * partB) {
      gemm_split_kernel<2><<<48*4*2, 256, 0, stream>>>(Kbf, LT, parts);
      reduce_kernel<<<768, 256, 0, stream>>>((const float4*)parts, (float4*)out, 2);
    } else {
      gemm_split_kernel<1><<<48*4, 256, 0, stream>>>(Kbf, LT, out);
    }
  } else {
    buildk_kernel<0><<<NN, 256, 0, stream>>>(coords, alpha, nullptr, Kout, nullptr);
    gemm_fallback<<<dim3(NN/128, DLAT/64), 256, 0, stream>>>(Kout, latent, out);
  }
}